// Round 1
// baseline (79.049 us; speedup 1.0000x reference)
//
#include <hip/hip_runtime.h>
#include <hip/hip_bf16.h>

namespace {

constexpr int Nn = 2048;
constexpr int Hh = 16;
constexpr int Dd = 64;
constexpr int ROWSTR = Hh * Dd;      // 1024 floats between consecutive tokens
constexpr int KVB = 64;              // KV tile rows
constexpr int NTILES = Nn / KVB;     // 32
constexpr int QB = 128;              // Q rows per block (4 waves x 32)
constexpr int NQT = Nn / QB;         // 16

typedef __bf16 bf16x8 __attribute__((ext_vector_type(8)));
typedef __bf16 bf16x4 __attribute__((ext_vector_type(4)));
typedef float  f32x16 __attribute__((ext_vector_type(16)));

// K tile: row-major [64][64] bf16, 128B rows, 16B-granule XOR swizzle (b128-read friendly)
__device__ __forceinline__ int swzK(int row, int colByte) {
  return (row * 128 + colByte) ^ ((row & 7) << 4);
}
// V^T tile: [d=64][kv=64] bf16, extra bit-3 XOR (b64 reads stay 8B-aligned, 2-way free)
__device__ __forceinline__ int swzV(int row, int colByte) {
  return (row * 128 + colByte) ^ (((row & 7) << 4) | (((row >> 3) & 1) << 3));
}

__global__ __launch_bounds__(256, 1) void fattn_kernel(
    const float* __restrict__ Qg, const float* __restrict__ Kg,
    const float* __restrict__ Vg, const int* __restrict__ flag,
    float* __restrict__ Og) {
  __shared__ __align__(16) char smem[2][16384];  // per buf: K 8KB @0, V^T 8KB @8192

  const int tid  = threadIdx.x;
  const int lane = tid & 63;
  const int wv   = tid >> 6;   // wave 0..3
  const int l31  = lane & 31;
  const int g2   = lane >> 5;  // 0/1

  // bid -> (bh, pair) with XCD grouping: bid%8 == bh>>2  (4 heads' K/V per XCD L2)
  const int bid = blockIdx.x;
  const int bh  = ((bid & 7) << 2) | (bid >> 6);
  const int pi  = (bid >> 3) & 7;      // pair index 0..7 -> qtiles {pi, 15-pi}
  const int b   = bh >> 4;
  const int h   = bh & 15;
  const int causal = flag[0];

  const size_t base = ((size_t)b * Nn * Hh + h) * Dd;
  const float* qp = Qg + base;
  const float* kp = Kg + base;
  const float* vp = Vg + base;
  float*       op = Og + base;

  const float SCALE = 0.125f * 1.44269504088896340736f;  // 1/sqrt(64) * log2(e)

  for (int pass = 0; pass < 2; ++pass) {
    const int Tq = pass ? (NQT - 1 - pi) : pi;
    const int qs = Tq * QB + wv * 32;                    // wave's first q row
    const int Tblock = causal ? (2 * Tq + 2) : NTILES;   // tiles staged by block
    const int Twave  = causal ? ((qs + 31) / KVB + 1) : NTILES;  // tiles computed by wave

    // ---- Q fragments in registers for the whole pass (contiguous k-slot map) ----
    bf16x8 qf[4];
#pragma unroll
    for (int dc = 0; dc < 4; ++dc) {
      const float* qrow = qp + (size_t)(qs + l31) * ROWSTR + dc * 16 + g2 * 8;
      float4 a = *(const float4*)qrow;
      float4 c = *(const float4*)(qrow + 4);
      qf[dc][0] = (__bf16)(a.x * SCALE); qf[dc][1] = (__bf16)(a.y * SCALE);
      qf[dc][2] = (__bf16)(a.z * SCALE); qf[dc][3] = (__bf16)(a.w * SCALE);
      qf[dc][4] = (__bf16)(c.x * SCALE); qf[dc][5] = (__bf16)(c.y * SCALE);
      qf[dc][6] = (__bf16)(c.z * SCALE); qf[dc][7] = (__bf16)(c.w * SCALE);
    }

    f32x16 acc0 = {};   // O cols 0..31  (col = l31)
    f32x16 acc1 = {};   // O cols 32..63
    float m_run = -INFINITY;
    float l_run = 0.0f;

    float4 kreg[4];
    float  vreg[16];

    // ---- prologue: stage tile 0 into buf 0 ----
    {
#pragma unroll
      for (int it = 0; it < 4; ++it) {
        int idx = it * 256 + tid;
        int kvr = idx >> 4, c4 = idx & 15;
        kreg[it] = *(const float4*)(kp + (size_t)kvr * ROWSTR + c4 * 4);
      }
#pragma unroll
      for (int it = 0; it < 4; ++it) {
        int idx = it * 256 + tid;
        int d8 = idx & 63, kv4 = idx >> 6;
#pragma unroll
        for (int i = 0; i < 4; ++i)
          vreg[it * 4 + i] = vp[(size_t)(kv4 * 4 + i) * ROWSTR + d8];
      }
      char* kb = smem[0];
      char* vb = smem[0] + 8192;
#pragma unroll
      for (int it = 0; it < 4; ++it) {
        int idx = it * 256 + tid;
        int kvr = idx >> 4, c4 = idx & 15;
        bf16x4 w = { (__bf16)kreg[it].x, (__bf16)kreg[it].y,
                     (__bf16)kreg[it].z, (__bf16)kreg[it].w };
        *(bf16x4*)(kb + swzK(kvr, c4 * 8)) = w;
      }
#pragma unroll
      for (int it = 0; it < 4; ++it) {
        int idx = it * 256 + tid;
        int d8 = idx & 63, kv4 = idx >> 6;
        bf16x4 w = { (__bf16)vreg[it * 4 + 0], (__bf16)vreg[it * 4 + 1],
                     (__bf16)vreg[it * 4 + 2], (__bf16)vreg[it * 4 + 3] };
        *(bf16x4*)(vb + swzV(d8, kv4 * 8)) = w;
      }
    }

    int cur = 0;
    for (int t = 0; t < Tblock; ++t) {
      __syncthreads();
      const bool prefetch = (t + 1 < Tblock);

      // T14: issue next tile's global loads before compute
      if (prefetch) {
        const int kv0 = (t + 1) * KVB;
#pragma unroll
        for (int it = 0; it < 4; ++it) {
          int idx = it * 256 + tid;
          int kvr = idx >> 4, c4 = idx & 15;
          kreg[it] = *(const float4*)(kp + (size_t)(kv0 + kvr) * ROWSTR + c4 * 4);
        }
#pragma unroll
        for (int it = 0; it < 4; ++it) {
          int idx = it * 256 + tid;
          int d8 = idx & 63, kv4 = idx >> 6;
#pragma unroll
          for (int i = 0; i < 4; ++i)
            vreg[it * 4 + i] = vp[(size_t)(kv0 + kv4 * 4 + i) * ROWSTR + d8];
        }
      }

      if (t < Twave) {
        const char* kb = smem[cur];
        const char* vb = smem[cur] + 8192;

        // ---- S^T = K . Q^T   (swapped: rows = kv, cols = q) ----
        f32x16 s0 = {}, s1 = {};
#pragma unroll
        for (int dc = 0; dc < 4; ++dc) {
          bf16x8 kf0 = *(const bf16x8*)(kb + swzK(l31,      32 * dc + 16 * g2));
          bf16x8 kf1 = *(const bf16x8*)(kb + swzK(32 + l31, 32 * dc + 16 * g2));
          s0 = __builtin_amdgcn_mfma_f32_32x32x16_bf16(kf0, qf[dc], s0, 0, 0, 0);
          s1 = __builtin_amdgcn_mfma_f32_32x32x16_bf16(kf1, qf[dc], s1, 0, 0, 0);
        }

        // ---- causal mask (only the wave's diagonal tile) ----
        if (causal && t == Twave - 1) {
          const int kvb = t * KVB;
          const int qrow = qs + l31;
#pragma unroll
          for (int r = 0; r < 16; ++r) {
            int rm = (r & 3) + ((r >> 2) << 3) + (g2 << 2);
            if (kvb + rm > qrow)      s0[r] = -INFINITY;
            if (kvb + 32 + rm > qrow) s1[r] = -INFINITY;
          }
        }

        // ---- online softmax (stats in q = l31 domain; 1 shfl_xor per reduce) ----
        float mt = -INFINITY;
#pragma unroll
        for (int r = 0; r < 16; ++r) { mt = fmaxf(mt, s0[r]); mt = fmaxf(mt, s1[r]); }
        mt = fmaxf(mt, __shfl_xor(mt, 32));
        const float mnew = fmaxf(m_run, mt);
        float rs = 0.0f;
#pragma unroll
        for (int r = 0; r < 16; ++r) {
          float p0 = exp2f(s0[r] - mnew);
          float p1 = exp2f(s1[r] - mnew);
          s0[r] = p0; s1[r] = p1;
          rs += p0 + p1;
        }
        rs += __shfl_xor(rs, 32);
        if (__all(mt <= m_run)) {          // no row max changed: skip rescale
          l_run += rs;
        } else {
          const float alpha = exp2f(m_run - mnew);
#pragma unroll
          for (int r = 0; r < 16; ++r) {
            float at = __shfl(alpha, (r & 3) + ((r >> 2) << 3) + (g2 << 2));
            acc0[r] *= at;
            acc1[r] *= at;
          }
          l_run = l_run * alpha + rs;
          m_run = mnew;
        }

        // ---- P fragments: direct pass-through of S^T regs (split-4 k-slot map) ----
        bf16x8 pa[4];
#pragma unroll
        for (int kc = 0; kc < 4; ++kc) {
          const f32x16& sv = (kc < 2) ? s0 : s1;
          const int rbase = (kc & 1) * 8;
#pragma unroll
          for (int j = 0; j < 8; ++j) pa[kc][j] = (__bf16)sv[rbase + j];
        }

        // ---- O += P . V  (V read d-major from V^T, split-4 k-slot map) ----
#pragma unroll
        for (int kc = 0; kc < 4; ++kc) {
          const int cb = 32 * kc + 8 * g2;
#pragma unroll
          for (int df = 0; df < 2; ++df) {
            const int row = 32 * df + l31;
            bf16x4 v0 = *(const bf16x4*)(vb + swzV(row, cb));
            bf16x4 v1 = *(const bf16x4*)(vb + swzV(row, cb + 16));
            bf16x8 vf = __builtin_shufflevector(v0, v1, 0, 1, 2, 3, 4, 5, 6, 7);
            if (df == 0)
              acc0 = __builtin_amdgcn_mfma_f32_32x32x16_bf16(pa[kc], vf, acc0, 0, 0, 0);
            else
              acc1 = __builtin_amdgcn_mfma_f32_32x32x16_bf16(pa[kc], vf, acc1, 0, 0, 0);
          }
        }
      }

      // T14: convert + write next tile into the other buffer after compute
      if (prefetch) {
        char* kb = smem[cur ^ 1];
        char* vb = smem[cur ^ 1] + 8192;
#pragma unroll
        for (int it = 0; it < 4; ++it) {
          int idx = it * 256 + tid;
          int kvr = idx >> 4, c4 = idx & 15;
          bf16x4 w = { (__bf16)kreg[it].x, (__bf16)kreg[it].y,
                       (__bf16)kreg[it].z, (__bf16)kreg[it].w };
          *(bf16x4*)(kb + swzK(kvr, c4 * 8)) = w;
        }
#pragma unroll
        for (int it = 0; it < 4; ++it) {
          int idx = it * 256 + tid;
          int d8 = idx & 63, kv4 = idx >> 6;
          bf16x4 w = { (__bf16)vreg[it * 4 + 0], (__bf16)vreg[it * 4 + 1],
                       (__bf16)vreg[it * 4 + 2], (__bf16)vreg[it * 4 + 3] };
          *(bf16x4*)(vb + swzV(d8, kv4 * 8)) = w;
        }
      }
      cur ^= 1;
    }

    // ---- epilogue: O = acc / l  (1/l shuffled into the C/D row domain) ----
    const float linv = 1.0f / l_run;
#pragma unroll
    for (int r = 0; r < 16; ++r) {
      const int rm = (r & 3) + ((r >> 2) << 3) + (g2 << 2);
      const float li = __shfl(linv, rm);
      const size_t row = (size_t)(qs + rm) * ROWSTR;
      op[row + l31]      = acc0[r] * li;
      op[row + 32 + l31] = acc1[r] * li;
    }
  }
}

}  // namespace

extern "C" void kernel_launch(void* const* d_in, const int* in_sizes, int n_in,
                              void* d_out, int out_size, void* d_ws, size_t ws_size,
                              hipStream_t stream) {
  (void)in_sizes; (void)n_in; (void)out_size; (void)d_ws; (void)ws_size;
  const float* q = (const float*)d_in[0];
  const float* k = (const float*)d_in[1];
  const float* v = (const float*)d_in[2];
  const int* flag = (const int*)d_in[3];
  float* out = (float*)d_out;
  fattn_kernel<<<dim3(256), dim3(256), 0, stream>>>(q, k, v, flag, out);
}

// Round 2
// 64.273 us; speedup vs baseline: 1.2299x; 1.2299x over previous
//
#include <hip/hip_runtime.h>
#include <hip/hip_bf16.h>

namespace {

constexpr int Nn = 2048;
constexpr int Hh = 16;
constexpr int Dd = 64;
constexpr int ROWSTR = Hh * Dd;      // 1024 floats between consecutive tokens
constexpr int KVB = 64;              // KV tile rows
constexpr int NTILES = Nn / KVB;     // 32
constexpr int QB = 128;              // Q rows per block (4 waves x 32)
constexpr int NQT = Nn / QB;         // 16

typedef __bf16 bf16x8 __attribute__((ext_vector_type(8)));
typedef __bf16 bf16x4 __attribute__((ext_vector_type(4)));
typedef float  f32x16 __attribute__((ext_vector_type(16)));

// K tile: row-major [64][64] bf16, 128B rows, 16B-granule XOR swizzle (b128-read friendly)
__device__ __forceinline__ int swzK(int row, int colByte) {
  return (row * 128 + colByte) ^ ((row & 7) << 4);
}
// V^T tile: [d=64][kv=64] bf16, extra bit-3 XOR (b64 reads stay 8B-aligned, 2-way free)
__device__ __forceinline__ int swzV(int row, int colByte) {
  return (row * 128 + colByte) ^ (((row & 7) << 4) | (((row >> 3) & 1) << 3));
}

__global__ __launch_bounds__(256, 2) void fattn_kernel(
    const float* __restrict__ Qg, const float* __restrict__ Kg,
    const float* __restrict__ Vg, const int* __restrict__ flag,
    float* __restrict__ Og) {
  __shared__ __align__(16) char smem[2][16384];  // per buf: K 8KB @0, V^T 8KB @8192

  const int tid  = threadIdx.x;
  const int lane = tid & 63;
  const int wv   = tid >> 6;   // wave 0..3
  const int l31  = lane & 31;
  const int g2   = lane >> 5;  // 0/1

  // grid = 512. Half 0 (bids 0..255) = heavy q-tiles (Tq=15..8), dispatched first;
  // half 1 (bids 256..511) = light q-tiles (Tq=7..0) co-resident as second block/CU.
  // Same rank -> same bh in both halves; bid&7 groups 4 heads per XCD L2.
  const int bid  = blockIdx.x;
  const int half = bid >> 8;
  const int r    = bid & 255;
  const int bh   = ((r & 7) << 2) | (r >> 6);
  const int ti   = (r >> 3) & 7;
  const int b    = bh >> 4;
  const int h    = bh & 15;
  const int causal = flag[0];
  const int Tq   = half ? ti : (NQT - 1 - ti);

  const size_t base = ((size_t)b * Nn * Hh + h) * Dd;
  const float* qp = Qg + base;
  const float* kp = Kg + base;
  const float* vp = Vg + base;
  float*       op = Og + base;

  const float SCALE = 0.125f * 1.44269504088896340736f;  // 1/sqrt(64) * log2(e)

  const int qs = Tq * QB + wv * 32;                    // wave's first q row
  const int Tblock = causal ? (2 * Tq + 2) : NTILES;   // tiles staged by block
  const int Twave  = causal ? ((qs + 31) / KVB + 1) : NTILES;  // tiles computed by wave

  // ---- Q fragments in registers (contiguous k-slot map) ----
  bf16x8 qf[4];
#pragma unroll
  for (int dc = 0; dc < 4; ++dc) {
    const float* qrow = qp + (size_t)(qs + l31) * ROWSTR + dc * 16 + g2 * 8;
    float4 a = *(const float4*)qrow;
    float4 c = *(const float4*)(qrow + 4);
    qf[dc][0] = (__bf16)(a.x * SCALE); qf[dc][1] = (__bf16)(a.y * SCALE);
    qf[dc][2] = (__bf16)(a.z * SCALE); qf[dc][3] = (__bf16)(a.w * SCALE);
    qf[dc][4] = (__bf16)(c.x * SCALE); qf[dc][5] = (__bf16)(c.y * SCALE);
    qf[dc][6] = (__bf16)(c.z * SCALE); qf[dc][7] = (__bf16)(c.w * SCALE);
  }

  f32x16 acc0 = {};   // O cols 0..31  (col = l31)
  f32x16 acc1 = {};   // O cols 32..63
  float m_run = -INFINITY;
  float l_run = 0.0f;

  float4 kreg[4];
  float  vreg[16];

  // ---- prologue: stage tile 0 into buf 0 ----
  {
#pragma unroll
    for (int it = 0; it < 4; ++it) {
      int idx = it * 256 + tid;
      int kvr = idx >> 4, c4 = idx & 15;
      kreg[it] = *(const float4*)(kp + (size_t)kvr * ROWSTR + c4 * 4);
    }
#pragma unroll
    for (int it = 0; it < 4; ++it) {
      int idx = it * 256 + tid;
      int d8 = idx & 63, kv4 = idx >> 6;
#pragma unroll
      for (int i = 0; i < 4; ++i)
        vreg[it * 4 + i] = vp[(size_t)(kv4 * 4 + i) * ROWSTR + d8];
    }
    char* kb = smem[0];
    char* vb = smem[0] + 8192;
#pragma unroll
    for (int it = 0; it < 4; ++it) {
      int idx = it * 256 + tid;
      int kvr = idx >> 4, c4 = idx & 15;
      bf16x4 w = { (__bf16)kreg[it].x, (__bf16)kreg[it].y,
                   (__bf16)kreg[it].z, (__bf16)kreg[it].w };
      *(bf16x4*)(kb + swzK(kvr, c4 * 8)) = w;
    }
#pragma unroll
    for (int it = 0; it < 4; ++it) {
      int idx = it * 256 + tid;
      int d8 = idx & 63, kv4 = idx >> 6;
      bf16x4 w = { (__bf16)vreg[it * 4 + 0], (__bf16)vreg[it * 4 + 1],
                   (__bf16)vreg[it * 4 + 2], (__bf16)vreg[it * 4 + 3] };
      *(bf16x4*)(vb + swzV(d8, kv4 * 8)) = w;
    }
  }

  int cur = 0;
  for (int t = 0; t < Tblock; ++t) {
    __syncthreads();
    const bool prefetch = (t + 1 < Tblock);

    // T14: issue next tile's global loads before compute
    if (prefetch) {
      const int kv0 = (t + 1) * KVB;
#pragma unroll
      for (int it = 0; it < 4; ++it) {
        int idx = it * 256 + tid;
        int kvr = idx >> 4, c4 = idx & 15;
        kreg[it] = *(const float4*)(kp + (size_t)(kv0 + kvr) * ROWSTR + c4 * 4);
      }
#pragma unroll
      for (int it = 0; it < 4; ++it) {
        int idx = it * 256 + tid;
        int d8 = idx & 63, kv4 = idx >> 6;
#pragma unroll
        for (int i = 0; i < 4; ++i)
          vreg[it * 4 + i] = vp[(size_t)(kv0 + kv4 * 4 + i) * ROWSTR + d8];
      }
    }

    if (t < Twave) {
      const char* kb = smem[cur];
      const char* vb = smem[cur] + 8192;

      // ---- S^T = K . Q^T   (swapped: rows = kv, cols = q) ----
      f32x16 s0 = {}, s1 = {};
#pragma unroll
      for (int dc = 0; dc < 4; ++dc) {
        bf16x8 kf0 = *(const bf16x8*)(kb + swzK(l31,      32 * dc + 16 * g2));
        bf16x8 kf1 = *(const bf16x8*)(kb + swzK(32 + l31, 32 * dc + 16 * g2));
        s0 = __builtin_amdgcn_mfma_f32_32x32x16_bf16(kf0, qf[dc], s0, 0, 0, 0);
        s1 = __builtin_amdgcn_mfma_f32_32x32x16_bf16(kf1, qf[dc], s1, 0, 0, 0);
      }

      // ---- causal mask (only the wave's diagonal tile) ----
      if (causal && t == Twave - 1) {
        const int kvb = t * KVB;
        const int qrow = qs + l31;
#pragma unroll
        for (int rr = 0; rr < 16; ++rr) {
          int rm = (rr & 3) + ((rr >> 2) << 3) + (g2 << 2);
          if (kvb + rm > qrow)      s0[rr] = -INFINITY;
          if (kvb + 32 + rm > qrow) s1[rr] = -INFINITY;
        }
      }

      // ---- online softmax (stats in q = l31 domain; 1 shfl_xor per reduce) ----
      float mt = -INFINITY;
#pragma unroll
      for (int rr = 0; rr < 16; ++rr) { mt = fmaxf(mt, s0[rr]); mt = fmaxf(mt, s1[rr]); }
      mt = fmaxf(mt, __shfl_xor(mt, 32));
      const float mnew = fmaxf(m_run, mt);
      float rs = 0.0f;
#pragma unroll
      for (int rr = 0; rr < 16; ++rr) {
        float p0 = exp2f(s0[rr] - mnew);
        float p1 = exp2f(s1[rr] - mnew);
        s0[rr] = p0; s1[rr] = p1;
        rs += p0 + p1;
      }
      rs += __shfl_xor(rs, 32);
      if (__all(mt <= m_run)) {          // no row max changed: skip rescale
        l_run += rs;
      } else {
        const float alpha = exp2f(m_run - mnew);
#pragma unroll
        for (int rr = 0; rr < 16; ++rr) {
          float at = __shfl(alpha, (rr & 3) + ((rr >> 2) << 3) + (g2 << 2));
          acc0[rr] *= at;
          acc1[rr] *= at;
        }
        l_run = l_run * alpha + rs;
        m_run = mnew;
      }

      // ---- P fragments: direct pass-through of S^T regs (split-4 k-slot map) ----
      bf16x8 pa[4];
#pragma unroll
      for (int kc = 0; kc < 4; ++kc) {
        const f32x16& sv = (kc < 2) ? s0 : s1;
        const int rbase = (kc & 1) * 8;
#pragma unroll
        for (int j = 0; j < 8; ++j) pa[kc][j] = (__bf16)sv[rbase + j];
      }

      // ---- O += P . V  (V read d-major from V^T, split-4 k-slot map) ----
#pragma unroll
      for (int kc = 0; kc < 4; ++kc) {
        const int cb = 32 * kc + 8 * g2;
#pragma unroll
        for (int df = 0; df < 2; ++df) {
          const int row = 32 * df + l31;
          bf16x4 v0 = *(const bf16x4*)(vb + swzV(row, cb));
          bf16x4 v1 = *(const bf16x4*)(vb + swzV(row, cb + 16));
          bf16x8 vf = __builtin_shufflevector(v0, v1, 0, 1, 2, 3, 4, 5, 6, 7);
          if (df == 0)
            acc0 = __builtin_amdgcn_mfma_f32_32x32x16_bf16(pa[kc], vf, acc0, 0, 0, 0);
          else
            acc1 = __builtin_amdgcn_mfma_f32_32x32x16_bf16(pa[kc], vf, acc1, 0, 0, 0);
        }
      }
    }

    // T14: convert + write next tile into the other buffer after compute
    if (prefetch) {
      char* kb = smem[cur ^ 1];
      char* vb = smem[cur ^ 1] + 8192;
#pragma unroll
      for (int it = 0; it < 4; ++it) {
        int idx = it * 256 + tid;
        int kvr = idx >> 4, c4 = idx & 15;
        bf16x4 w = { (__bf16)kreg[it].x, (__bf16)kreg[it].y,
                     (__bf16)kreg[it].z, (__bf16)kreg[it].w };
        *(bf16x4*)(kb + swzK(kvr, c4 * 8)) = w;
      }
#pragma unroll
      for (int it = 0; it < 4; ++it) {
        int idx = it * 256 + tid;
        int d8 = idx & 63, kv4 = idx >> 6;
        bf16x4 w = { (__bf16)vreg[it * 4 + 0], (__bf16)vreg[it * 4 + 1],
                     (__bf16)vreg[it * 4 + 2], (__bf16)vreg[it * 4 + 3] };
        *(bf16x4*)(vb + swzV(d8, kv4 * 8)) = w;
      }
    }
    cur ^= 1;
  }

  // ---- epilogue: O = acc / l  (1/l shuffled into the C/D row domain) ----
  const float linv = 1.0f / l_run;
#pragma unroll
  for (int rr = 0; rr < 16; ++rr) {
    const int rm = (rr & 3) + ((rr >> 2) << 3) + (g2 << 2);
    const float li = __shfl(linv, rm);
    const size_t row = (size_t)(qs + rm) * ROWSTR;
    op[row + l31]      = acc0[rr] * li;
    op[row + 32 + l31] = acc1[rr] * li;
  }
}

}  // namespace

extern "C" void kernel_launch(void* const* d_in, const int* in_sizes, int n_in,
                              void* d_out, int out_size, void* d_ws, size_t ws_size,
                              hipStream_t stream) {
  (void)in_sizes; (void)n_in; (void)out_size; (void)d_ws; (void)ws_size;
  const float* q = (const float*)d_in[0];
  const float* k = (const float*)d_in[1];
  const float* v = (const float*)d_in[2];
  const int* flag = (const int*)d_in[3];
  float* out = (float*)d_out;
  fattn_kernel<<<dim3(512), dim3(256), 0, stream>>>(q, k, v, flag, out);
}